// Round 3
// baseline (1963.504 us; speedup 1.0000x reference)
//
#include <hip/hip_runtime.h>
#include <hip/hip_bf16.h>
#include <math.h>

// ---------------------------------------------------------------------------
// SelfInteractionUNet on MI355X — round 2.
// Round-1 crash diagnosis: ws footprint 304 MB > ws_size (round 0 proved
// >=219 MB is fine). Fix: state (4*NM fp32 = 67.1 MB) now lives in d_out
// (exact fit; final gating kernel reads only h/s2/v2, so overwriting d_out
// with the final output is race-free). ws = 237 MB fp32-temps path, with a
// runtime fp16-temps fallback (195 MB) if ws_size is tighter.
// GEMMs: split-bf16 (hi+lo) 3-term MFMA: A*B ~= Ah*Bh + Al*Bh + Ah*Bl.
// ---------------------------------------------------------------------------

typedef __attribute__((ext_vector_type(8))) short bf16x8;
typedef __attribute__((ext_vector_type(4))) short bf16x4;
typedef __attribute__((ext_vector_type(4))) float f32x4;
typedef __attribute__((ext_vector_type(4))) _Float16 f16x4;

__device__ __forceinline__ float bf2f(unsigned short u){
  union { unsigned int i; float f; } x; x.i = ((unsigned int)u) << 16; return x.f;
}
__device__ __forceinline__ unsigned short f2bf(float f){
  union { float f; unsigned int i; } x; x.f = f;
  unsigned int i = x.i;
  return (unsigned short)((i + 0x7fffu + ((i >> 16) & 1u)) >> 16);
}

__device__ __forceinline__ f32x4 ld4f(const float* p){ return *(const f32x4*)p; }
__device__ __forceinline__ f32x4 ld4f(const _Float16* p){
  f16x4 v = *(const f16x4*)p;
  f32x4 r;
  #pragma unroll
  for (int j = 0; j < 4; ++j) r[j] = (float)v[j];
  return r;
}

// ---------------------------------------------------------------------------
// Weight transpose + fp32 -> split bf16: W [9][K][Mo] f32 -> Wh/Wl [9][Mo][K]
// ---------------------------------------------------------------------------
__global__ __launch_bounds__(256)
void transpose_w(const float* __restrict__ W, unsigned short* __restrict__ Wh,
                 unsigned short* __restrict__ Wl, int K, int Mo){
  __shared__ float tile[32][33];
  const int bi = blockIdx.z;
  const float* Wb = W + (size_t)bi * K * Mo;
  const size_t wo = (size_t)bi * K * Mo;
  const int k0 = blockIdx.x * 32, o0 = blockIdx.y * 32;
  const int tx = threadIdx.x & 31, ty = threadIdx.x >> 5;  // 32 x 8
  #pragma unroll
  for (int i = 0; i < 4; ++i){
    int k = ty + i * 8;
    tile[k][tx] = Wb[(size_t)(k0 + k) * Mo + o0 + tx];
  }
  __syncthreads();
  #pragma unroll
  for (int i = 0; i < 4; ++i){
    int o = ty + i * 8;
    float f = tile[tx][o];
    unsigned short h = f2bf(f);
    unsigned short l = f2bf(f - bf2f(h));
    Wh[wo + (size_t)(o0 + o) * K + k0 + tx] = h;
    Wl[wo + (size_t)(o0 + o) * K + k0 + tx] = l;
  }
}

// ---------------------------------------------------------------------------
// Inputs -> fp32 planes in d_out. s[N][256], v[N][256][3] -> [s|v0|v1|v2]
// ---------------------------------------------------------------------------
__global__ __launch_bounds__(256)
void convert_inputs(const float* __restrict__ s, const float* __restrict__ v,
                    float* __restrict__ st, int NM){
  int i = blockIdx.x * 256 + threadIdx.x;
  if (i >= NM) return;
  st[i] = s[i];
  const float* vp = v + (size_t)i * 3;
  st[(size_t)NM + i]     = vp[0];
  st[(size_t)2 * NM + i] = vp[1];
  st[(size_t)3 * NM + i] = vp[2];
}

// ---------------------------------------------------------------------------
// GEMM: C[N x Mo] = A[N x K] @ B[K x Mo]. A fp32/ST (possibly generated on
// the fly), split to bf16 hi/lo in staging. B pre-split Bh/Bl [Mo][K] bf16.
// 128x128 tile, 4 waves (2x2), 16x16x32 MFMA, 3-term split accumulate.
// ST: storage type of s2/v2/h temporaries (float or _Float16).
// AMODE: 0 = plain A (ST row-major [N][K])
//        1 = s_in gen: [s | s^2 | |v|^2/sqrt(3)]          (K=768)
//        2 = v_in gen for plane d=blockIdx.z: [v_d | sqrt2*s*v_d]  (K=512)
// EPI:   0 = store ST (scaled);  1 = silu -> ST
//        2 = g=silu; gate s2/v2 -> state fp32
//        3 = g=silu; gate s2/v2 -> final fp32 output (interleaved v)
// ---------------------------------------------------------------------------
template<typename ST, int AMODE, int EPI>
__global__ __launch_bounds__(256)
void gemm_k(const ST* __restrict__ Ap,
            const float* __restrict__ St,
            const unsigned short* __restrict__ Bh,
            const unsigned short* __restrict__ Bl,
            int K, int Mo, int NM, float scale,
            ST* __restrict__ outf,
            const ST* __restrict__ s2g,
            const ST* __restrict__ v2g,
            float* __restrict__ stout,
            float* __restrict__ fout)
{
  __shared__ unsigned short Ah[128][40];   // +8 pad
  __shared__ unsigned short Al[128][40];
  __shared__ unsigned short Bhs[128][40];
  __shared__ unsigned short Bls[128][40];
  const int tid  = threadIdx.x;
  const int lane = tid & 63;
  const int wave = tid >> 6;
  const int wrow = (wave >> 1) * 64;
  const int wcol = (wave & 1) * 64;
  const int row0 = blockIdx.x * 128;
  const int col0 = blockIdx.y * 128;
  int dplane = 0;
  if (AMODE == 2){ dplane = blockIdx.z; outf += (size_t)dplane * NM; }

  f32x4 acc[4][4];
  #pragma unroll
  for (int m = 0; m < 4; ++m)
    #pragma unroll
    for (int n = 0; n < 4; ++n) acc[m][n] = (f32x4){0.f, 0.f, 0.f, 0.f};

  for (int k0 = 0; k0 < K; k0 += 32){
    const int seg = k0 >> 8;           // uniform per k-tile
    // ---- A staging: fp32 -> split hi/lo bf16
    #pragma unroll
    for (int it = 0; it < 4; ++it){
      int idx = tid + it * 256;
      int r   = idx >> 3;              // 0..127
      int c4  = (idx & 7) * 4;         // k offset in tile
      int gr  = row0 + r;
      int gk  = k0 + c4;
      f32x4 f;
      if (AMODE == 0){
        f = ld4f(Ap + (size_t)gr * K + gk);
      } else {
        int c = gk & 255;
        const size_t o = (size_t)gr * 256 + c;
        if (AMODE == 1){
          if (seg == 0){
            f = *(const f32x4*)(St + o);
          } else if (seg == 1){
            f32x4 x = *(const f32x4*)(St + o);
            #pragma unroll
            for (int j = 0; j < 4; ++j) f[j] = x[j] * x[j];
          } else {
            f32x4 a0 = *(const f32x4*)(St + (size_t)NM + o);
            f32x4 a1 = *(const f32x4*)(St + (size_t)2 * NM + o);
            f32x4 a2 = *(const f32x4*)(St + (size_t)3 * NM + o);
            #pragma unroll
            for (int j = 0; j < 4; ++j)
              f[j] = (a0[j]*a0[j] + a1[j]*a1[j] + a2[j]*a2[j]) * 0.57735026918962576f;
          }
        } else {
          const float* vd = St + (size_t)(1 + dplane) * NM;
          if (seg == 0){
            f = *(const f32x4*)(vd + o);
          } else {
            f32x4 sv = *(const f32x4*)(St + o);
            f32x4 vv = *(const f32x4*)(vd + o);
            #pragma unroll
            for (int j = 0; j < 4; ++j)
              f[j] = 1.41421356237309505f * sv[j] * vv[j];
          }
        }
      }
      bf16x4 hi, lo;
      #pragma unroll
      for (int j = 0; j < 4; ++j){
        unsigned short h = f2bf(f[j]);
        hi[j] = (short)h;
        lo[j] = (short)f2bf(f[j] - bf2f(h));
      }
      *(bf16x4*)(&Ah[r][c4]) = hi;
      *(bf16x4*)(&Al[r][c4]) = lo;
    }
    // ---- B staging: pre-split bf16 copies
    #pragma unroll
    for (int it = 0; it < 2; ++it){
      int idx = tid + it * 256;
      int r   = idx >> 2;
      int kc  = (idx & 3) * 8;
      const size_t o = (size_t)(col0 + r) * K + k0 + kc;
      *(bf16x8*)(&Bhs[r][kc]) = *(const bf16x8*)(Bh + o);
      *(bf16x8*)(&Bls[r][kc]) = *(const bf16x8*)(Bl + o);
    }
    __syncthreads();

    const int arow = lane & 15;
    const int kq   = (lane >> 4) * 8;
    bf16x8 ah[4], al[4], bh[4], bl[4];
    #pragma unroll
    for (int m = 0; m < 4; ++m){
      ah[m] = *(const bf16x8*)(&Ah[wrow + m*16 + arow][kq]);
      al[m] = *(const bf16x8*)(&Al[wrow + m*16 + arow][kq]);
    }
    #pragma unroll
    for (int n = 0; n < 4; ++n){
      bh[n] = *(const bf16x8*)(&Bhs[wcol + n*16 + arow][kq]);
      bl[n] = *(const bf16x8*)(&Bls[wcol + n*16 + arow][kq]);
    }
    #pragma unroll
    for (int m = 0; m < 4; ++m)
      #pragma unroll
      for (int n = 0; n < 4; ++n){
        acc[m][n] = __builtin_amdgcn_mfma_f32_16x16x32_bf16(ah[m], bh[n], acc[m][n], 0, 0, 0);
        acc[m][n] = __builtin_amdgcn_mfma_f32_16x16x32_bf16(al[m], bh[n], acc[m][n], 0, 0, 0);
        acc[m][n] = __builtin_amdgcn_mfma_f32_16x16x32_bf16(ah[m], bl[n], acc[m][n], 0, 0, 0);
      }
    __syncthreads();
  }

  // epilogue: C/D layout (m89): col = lane&15, row = (lane>>4)*4 + j
  #pragma unroll
  for (int m = 0; m < 4; ++m){
    #pragma unroll
    for (int n = 0; n < 4; ++n){
      const int cg = col0 + wcol + n * 16 + (lane & 15);
      #pragma unroll
      for (int j = 0; j < 4; ++j){
        const int rg = row0 + wrow + m * 16 + ((lane >> 4) * 4) + j;
        float val = acc[m][n][j] * scale;
        if (EPI == 0){
          outf[(size_t)rg * Mo + cg] = (ST)val;
        } else if (EPI == 1){
          outf[(size_t)rg * Mo + cg] = (ST)(val / (1.f + expf(-val)));
        } else {
          float gv = val / (1.f + expf(-val));   // silu
          if (cg < 256){
            float sval = (float)s2g[(size_t)rg * 256 + cg] * gv;
            if (EPI == 2) stout[(size_t)rg * 256 + cg] = sval;
            else          fout[(size_t)rg * 1024 + cg] = sval;
          } else {
            int c = cg - 256;
            #pragma unroll
            for (int d = 0; d < 3; ++d){
              float vv = (float)v2g[(size_t)d * NM + (size_t)rg * 256 + c] * gv;
              if (EPI == 2) stout[(size_t)(1 + d) * NM + (size_t)rg * 256 + c] = vv;
              else          fout[(size_t)rg * 1024 + 256 + 3 * (size_t)c + d] = vv;
            }
          }
        }
      }
    }
  }
}

// ---------------------------------------------------------------------------
// Equivariant layernorm: one wave per row, 4 cols/lane. Optional fp16 snap.
// ---------------------------------------------------------------------------
__global__ __launch_bounds__(256)
void ln_k(float* __restrict__ st, _Float16* __restrict__ snap, int NM){
  const int row  = blockIdx.x * 4 + (threadIdx.x >> 6);
  const int lane = threadIdx.x & 63;
  const size_t o = (size_t)row * 256 + lane * 4;
  f32x4 sv = *(const f32x4*)(st + o);
  f32x4 v0 = *(const f32x4*)(st + (size_t)NM + o);
  f32x4 v1 = *(const f32x4*)(st + (size_t)2 * NM + o);
  f32x4 v2 = *(const f32x4*)(st + (size_t)3 * NM + o);
  float r0 = 0.f, r1 = 0.f, r2 = 0.f;
  #pragma unroll
  for (int j = 0; j < 4; ++j){
    r0 += sv[j];
    r1 += sv[j] * sv[j];
    r2 += v0[j]*v0[j] + v1[j]*v1[j] + v2[j]*v2[j];
  }
  #pragma unroll
  for (int off = 1; off < 64; off <<= 1){
    r0 += __shfl_xor(r0, off, 64);
    r1 += __shfl_xor(r1, off, 64);
    r2 += __shfl_xor(r2, off, 64);
  }
  float mu  = r0 * (1.f / 256.f);
  float var = r1 * (1.f / 256.f) - mu * mu;
  float srs = rsqrtf(var + 1e-6f);
  float vrs = rsqrtf(r2 * (1.f / 768.f) + 1e-6f);
  f32x4 so, w0, w1, w2;
  #pragma unroll
  for (int j = 0; j < 4; ++j){
    so[j] = (sv[j] - mu) * srs;
    w0[j] = v0[j] * vrs; w1[j] = v1[j] * vrs; w2[j] = v2[j] * vrs;
  }
  *(f32x4*)(st + o) = so;
  *(f32x4*)(st + (size_t)NM + o) = w0;
  *(f32x4*)(st + (size_t)2*NM + o) = w1;
  *(f32x4*)(st + (size_t)3*NM + o) = w2;
  if (snap){
    f16x4 h0, h1, h2, h3;
    #pragma unroll
    for (int j = 0; j < 4; ++j){
      h0[j] = (_Float16)so[j]; h1[j] = (_Float16)w0[j];
      h2[j] = (_Float16)w1[j]; h3[j] = (_Float16)w2[j];
    }
    *(f16x4*)(snap + o) = h0;
    *(f16x4*)(snap + (size_t)NM + o) = h1;
    *(f16x4*)(snap + (size_t)2*NM + o) = h2;
    *(f16x4*)(snap + (size_t)3*NM + o) = h3;
  }
}

// ---------------------------------------------------------------------------
// state(fp32) += skip(fp16), 4-wide
// ---------------------------------------------------------------------------
__global__ __launch_bounds__(256)
void add_k(float* __restrict__ a, const _Float16* __restrict__ b, int n4){
  int i = blockIdx.x * 256 + threadIdx.x;
  if (i >= n4) return;
  f32x4 av = ((const f32x4*)a)[i];
  f16x4 bv = ((const f16x4*)b)[i];
  #pragma unroll
  for (int j = 0; j < 4; ++j) av[j] += (float)bv[j];
  ((f32x4*)a)[i] = av;
}

// ---------------------------------------------------------------------------
// Full pipeline, templated on the temp-storage type ST (float or _Float16).
// ---------------------------------------------------------------------------
template<typename ST>
static void run_unet(const unsigned short* W0h, const unsigned short* W0l,
                     const unsigned short* W1h, const unsigned short* W1l,
                     const unsigned short* Wah, const unsigned short* Wal,
                     const unsigned short* Wbh, const unsigned short* Wbl,
                     float* state, ST* s2, ST* v2, ST* h, _Float16* skips,
                     float* out, int N, int NM, hipStream_t stream){
  dim3 blk(256);
  const float c_s2 = 1.f / sqrtf(768.f);
  const float c_v2 = 1.f / sqrtf(512.f);
  const float c_hg = 1.f / 16.f;             // 1/sqrt(256)
  const int gx = N / 128;

  auto run_block = [&](int i, bool fin){
    const unsigned short* w0h = W0h + (size_t)i * 768 * 256;
    const unsigned short* w0l = W0l + (size_t)i * 768 * 256;
    const unsigned short* w1h = W1h + (size_t)i * 512 * 256;
    const unsigned short* w1l = W1l + (size_t)i * 512 * 256;
    const unsigned short* wah = Wah + (size_t)i * 256 * 256;
    const unsigned short* wal = Wal + (size_t)i * 256 * 256;
    const unsigned short* wbh = Wbh + (size_t)i * 256 * 512;
    const unsigned short* wbl = Wbl + (size_t)i * 256 * 512;
    gemm_k<ST,1,0><<<dim3(gx, 2, 1), blk, 0, stream>>>(nullptr, state, w0h, w0l, 768, 256, NM, c_s2,
                                                       s2, nullptr, nullptr, nullptr, nullptr);
    gemm_k<ST,2,0><<<dim3(gx, 2, 3), blk, 0, stream>>>(nullptr, state, w1h, w1l, 512, 256, NM, c_v2,
                                                       v2, nullptr, nullptr, nullptr, nullptr);
    gemm_k<ST,0,1><<<dim3(gx, 2, 1), blk, 0, stream>>>(s2, nullptr, wah, wal, 256, 256, NM, c_hg,
                                                       h, nullptr, nullptr, nullptr, nullptr);
    if (!fin)
      gemm_k<ST,0,2><<<dim3(gx, 4, 1), blk, 0, stream>>>(h, nullptr, wbh, wbl, 256, 512, NM, c_hg,
                                                         nullptr, s2, v2, state, nullptr);
    else
      gemm_k<ST,0,3><<<dim3(gx, 4, 1), blk, 0, stream>>>(h, nullptr, wbh, wbl, 256, 512, NM, c_hg,
                                                         nullptr, s2, v2, nullptr, out);
  };

  for (int i = 0; i < 4; ++i){
    run_block(i, false);
    ln_k<<<dim3(N/4), blk, 0, stream>>>(state, skips + (size_t)i * 4 * NM, NM);
  }
  run_block(4, false);
  for (int j = 0; j < 4; ++j){
    add_k<<<dim3(NM / 256), blk, 0, stream>>>(state, skips + (size_t)(3 - j) * 4 * NM, NM);
    run_block(5 + j, j == 3);
    if (j < 3) ln_k<<<dim3(N/4), blk, 0, stream>>>(state, nullptr, NM);
  }
}

// ---------------------------------------------------------------------------
extern "C" void kernel_launch(void* const* d_in, const int* in_sizes, int n_in,
                              void* d_out, int out_size, void* d_ws, size_t ws_size,
                              hipStream_t stream){
  const float* s_in = (const float*)d_in[0];
  const float* v_in = (const float*)d_in[1];
  const float* W0 = (const float*)d_in[2];   // [9][768][256]
  const float* W1 = (const float*)d_in[3];   // [9][512][256]
  const float* Wa = (const float*)d_in[4];   // [9][256][256]
  const float* Wb = (const float*)d_in[5];   // [9][256][512]
  const int Mdim = 256;
  const int N  = in_sizes[0] / Mdim;         // 16384
  const int NM = N * Mdim;

  char* ws = (char*)d_ws;
  size_t off = 0;
  auto allocS = [&](size_t elems){ unsigned short* p = (unsigned short*)(ws + off); off += elems * 2; return p; };
  unsigned short* W0h = allocS((size_t)9 * 768 * 256);
  unsigned short* W0l = allocS((size_t)9 * 768 * 256);
  unsigned short* W1h = allocS((size_t)9 * 512 * 256);
  unsigned short* W1l = allocS((size_t)9 * 512 * 256);
  unsigned short* Wah = allocS((size_t)9 * 256 * 256);
  unsigned short* Wal = allocS((size_t)9 * 256 * 256);
  unsigned short* Wbh = allocS((size_t)9 * 256 * 512);
  unsigned short* Wbl = allocS((size_t)9 * 256 * 512);
  const size_t weights_bytes = off;
  const size_t skips_bytes   = (size_t)16 * NM * 2;           // 4 snaps x 4 planes fp16
  const size_t temps32_bytes = (size_t)5 * NM * 4;            // s2 + 3*v2 + h fp32
  const bool use_f32 = (ws_size == 0) ||                      // unknown -> assume big
                       (ws_size >= weights_bytes + temps32_bytes + skips_bytes);

  // state lives in d_out: 4*NM fp32 == out_size*4 bytes exactly.
  float* state = (float*)d_out;

  dim3 blk(256);
  transpose_w<<<dim3(768/32, 256/32, 9), blk, 0, stream>>>(W0, W0h, W0l, 768, 256);
  transpose_w<<<dim3(512/32, 256/32, 9), blk, 0, stream>>>(W1, W1h, W1l, 512, 256);
  transpose_w<<<dim3(256/32, 256/32, 9), blk, 0, stream>>>(Wa, Wah, Wal, 256, 256);
  transpose_w<<<dim3(256/32, 512/32, 9), blk, 0, stream>>>(Wb, Wbh, Wbl, 256, 512);
  convert_inputs<<<dim3(NM/256), blk, 0, stream>>>(s_in, v_in, state, NM);

  if (use_f32){
    float* s2 = (float*)(ws + off);
    float* v2 = s2 + NM;
    float* h  = v2 + (size_t)3 * NM;
    _Float16* skips = (_Float16*)(h + NM);
    run_unet<float>(W0h, W0l, W1h, W1l, Wah, Wal, Wbh, Wbl,
                    state, s2, v2, h, skips, (float*)d_out, N, NM, stream);
  } else {
    _Float16* s2 = (_Float16*)(ws + off);
    _Float16* v2 = s2 + NM;
    _Float16* h  = v2 + (size_t)3 * NM;
    _Float16* skips = h + NM;
    run_unet<_Float16>(W0h, W0l, W1h, W1l, Wah, Wal, Wbh, Wbl,
                       state, s2, v2, h, skips, (float*)d_out, N, NM, stream);
  }
}